// Round 8
// baseline (16425.825 us; speedup 1.0000x reference)
//
#include <hip/hip_runtime.h>

typedef _Float16 half_t;
typedef _Float16 half2_t __attribute__((ext_vector_type(2)));
typedef unsigned int       u32;
typedef unsigned short     u16;

#define BB    32      // batch (chains)
#define TT    2048    // seq len
#define HH    256     // hidden = input dim
#define DEPTH 8       // ring depth (power of 2)

// ws layout (bytes), total 1,900,544:
//   0       : flags[8 links][BB] monotonic u32, padded 128B each   (32768)
//   32768   : cons [8 links][BB][4 consumer slots] u32, 128B pad   (32768)
//   65536   : xgq[4][BB][DEPTH][384] f32  (1572864)   links 0,1,4,5
//   1638400 : hq [4][BB][DEPTH][64]  u32  (262144)    links 2,3,6,7 (128 f16 each)
#define OFF_CONS 32768
#define OFF_XGQ  65536
#define OFF_HQ   1638400
#define FLAGS_BYTES 65536

__device__ __forceinline__ half2_t f2h2(float a, float b) {
  half2_t r; r.x = (half_t)a; r.y = (half_t)b; return r;
}
__device__ __forceinline__ float sigm(float v) {
  return __builtin_amdgcn_rcpf(1.f + __builtin_amdgcn_exp2f(v * -1.4426950408889634f));
}
__device__ __forceinline__ float tanh_fast(float v) {
  return 1.f - 2.f * __builtin_amdgcn_rcpf(1.f + __builtin_amdgcn_exp2f(v * 2.8853900817779268f));
}
__device__ __forceinline__ void wait_ge(u32* p, u32 v) {
  while (__hip_atomic_load(p, __ATOMIC_ACQUIRE, __HIP_MEMORY_SCOPE_AGENT) < v) {}
}
__device__ __forceinline__ float ld_f32_agent(const float* p) {
  return __hip_atomic_load(p, __ATOMIC_RELAXED, __HIP_MEMORY_SCOPE_AGENT);
}
__device__ __forceinline__ u32 ld_u32_agent(const u32* p) {
  return __hip_atomic_load(p, __ATOMIC_RELAXED, __HIP_MEMORY_SCOPE_AGENT);
}
__device__ __forceinline__ void st_f32_agent(float* p, float v) {
  __hip_atomic_store(p, v, __ATOMIC_RELAXED, __HIP_MEMORY_SCOPE_AGENT);
}
__device__ __forceinline__ void st_u16_agent(u16* p, u16 v) {
  __hip_atomic_store(p, v, __ATOMIC_RELAXED, __HIP_MEMORY_SCOPE_AGENT);
}

// 256 blocks = 8 stages x 32 chains; blockIdx = stage*32 + chain (stage stride 32 ≡ 0 mod 8
// -> all stages of a chain land on the same XCD under round-robin dispatch).
// stages: 0/1 = xg0 halves (Wih0)   2/3 = cell0 halves (Whh0, h-exchange via L2)
//         4/5 = xg1 halves (Wih1)   6/7 = cell1 halves (Whh1) -> out + h-exchange
// Each stage: 384 rows x 256 k over 512 threads; thread (i=tid>>2 in [0,128), c=tid&3)
// owns rows {half*128+i, 256+half*128+i, 512+half*128+i} x k in [c*64,(c+1)*64):
// 96 weight u32/thread -> fits the 128-VGPR @4-waves/EU budget the backend insists on
// (R4/R5/R7: every attempt at >128 VGPRs was refused; 192-reg designs spill/restream).
// asm laundering keeps the weight regs alive (R6: without it the loads get re-materialized
// into the t-loop, 384KB/step L2 restream).
__global__ __launch_bounds__(512) __attribute__((amdgpu_waves_per_eu(2, 4)))
void gru_pipe(const float* __restrict__ x,     // fp32 [B][T][H]
              const float* __restrict__ Wih,   // fp32 [2][768][256]
              const float* __restrict__ Whh,   // fp32 [2][768][256]
              const float* __restrict__ bih,   // fp32 [2][768]
              const float* __restrict__ bhh,   // fp32 [2][768]
              float* __restrict__ out,         // fp32 [B][T][H]
              uint8_t* __restrict__ ws)
{
  const int stage = blockIdx.x >> 5;
  const int chain = blockIdx.x & 31;
  const int tid   = threadIdx.x;
  const int i     = tid >> 2;     // 0..127
  const int c     = tid & 3;      // k-quarter
  const int func  = stage >> 1;   // 0 xg0, 1 cell0, 2 xg1, 3 cell1
  const int half  = stage & 1;
  const int layer = func >> 1;
  const bool cell = func & 1;

  u32*   flags = (u32*)ws;
  u32*   cons  = (u32*)(ws + OFF_CONS);
  float* xgq   = (float*)(ws + OFF_XGQ);
  u32*   hq    = (u32*)(ws + OFF_HQ);

  // ---- link topology ----
  int inA = -1, inB = -1, idxA = 0, idxB = 0, outL, nconsO = 1;
  if (func == 0)      { outL = half; }
  else if (func == 1) { inA = half;     inB = 3 - half;       outL = 2 + half; nconsO = 3; }
  else if (func == 2) { inA = 2;        inB = 3;  idxA = idxB = 1 + half; outL = 4 + half; }
  else                { inA = 4 + half; inB = 6 + (1 - half); outL = 6 + half; }

  u32* fA = (inA >= 0) ? flags + (size_t)(inA * BB + chain) * 32 : nullptr;
  u32* fB = (inB >= 0) ? flags + (size_t)(inB * BB + chain) * 32 : nullptr;
  u32* fO = flags + (size_t)(outL * BB + chain) * 32;
  u32* cO = cons  + (size_t)(outL * BB + chain) * 32;
  u32* cA = (inA >= 0) ? cons + (size_t)(inA * BB + chain) * 32 + idxA : nullptr;
  u32* cB = (inB >= 0) ? cons + (size_t)(inB * BB + chain) * 32 + idxB : nullptr;

  // payload bases (slot-invariant parts)
  float* xg_in  = (!cell || inA < 0) ? nullptr
                : xgq + (size_t)(((inA < 2 ? inA : inA - 2) * BB + chain)) * DEPTH * 384;
  float* xg_out = cell ? nullptr
                : xgq + (size_t)(((outL < 2 ? outL : outL - 2) * BB + chain)) * DEPTH * 384;
  u32* hq_pn = nullptr, *hq_out = nullptr, *hq_a = nullptr, *hq_b = nullptr;
  if (cell) {
    int qi = (inB == 2) ? 0 : (inB == 3) ? 1 : (inB == 6) ? 2 : 3;
    int qo = (outL == 2) ? 0 : (outL == 3) ? 1 : (outL == 6) ? 2 : 3;
    hq_pn  = hq + (size_t)(qi * BB + chain) * DEPTH * 64;
    hq_out = hq + (size_t)(qo * BB + chain) * DEPTH * 64;
  } else if (func == 2) {
    hq_a = hq + (size_t)(0 * BB + chain) * DEPTH * 64;   // link2 payload (h0 half A)
    hq_b = hq + (size_t)(1 * BB + chain) * DEPTH * 64;   // link3 payload (h0 half B)
  }

  // ---- weights -> 96 VGPRs (fp32 -> f16 RNE), laundered against remat ----
  const float* Wm = (cell ? Whh : Wih) + (size_t)layer * 768 * HH;
  const float* bv = (cell ? bhh : bih) + (size_t)layer * 768;
  u32 w0[32], w1[32], w2[32];
  float bs0, bs1, bs2;
  {
    const int r0 = half * 128 + i;
    const float4* p0 = (const float4*)(Wm + (size_t)(r0)       * HH + c * 64);
    const float4* p1 = (const float4*)(Wm + (size_t)(r0 + 256) * HH + c * 64);
    const float4* p2 = (const float4*)(Wm + (size_t)(r0 + 512) * HH + c * 64);
#pragma unroll
    for (int j = 0; j < 16; ++j) {
      float4 a = p0[j], b = p1[j], d = p2[j];
      w0[2*j] = __builtin_bit_cast(u32, f2h2(a.x, a.y)); w0[2*j+1] = __builtin_bit_cast(u32, f2h2(a.z, a.w));
      w1[2*j] = __builtin_bit_cast(u32, f2h2(b.x, b.y)); w1[2*j+1] = __builtin_bit_cast(u32, f2h2(b.z, b.w));
      w2[2*j] = __builtin_bit_cast(u32, f2h2(d.x, d.y)); w2[2*j+1] = __builtin_bit_cast(u32, f2h2(d.z, d.w));
    }
    bs0 = bv[r0]; bs1 = bv[r0 + 256]; bs2 = bv[r0 + 512];
  }
#pragma unroll
  for (int j = 0; j < 32; ++j) {
    asm volatile("" : "+v"(w0[j]));
    asm volatile("" : "+v"(w1[j]));
    asm volatile("" : "+v"(w2[j]));
  }

  __shared__ __align__(16) half2_t hb[2][128];   // ping-pong 256-f16 input vector
  u32* hbu = (u32*)hb;
  if (tid < 128) { hbu[tid] = 0u; hbu[128 + tid] = 0u; }

  float   hprev = 0.f;
  half2_t xreg; xreg.x = (half_t)0.f; xreg.y = (half_t)0.f;
  if (func == 0 && tid < 128) {
    float2 v = ((const float2*)(x + (size_t)(chain * TT) * HH))[tid];
    xreg = f2h2(v.x, v.y);
  }
  u32 cc0 = 0, cc1 = 0, cc2 = 0;   // cached consumer credits (tid0)

  __syncthreads();

  for (int t = 0; t < TT; ++t) {
    const int slot = t & (DEPTH - 1);
    float xr = 0.f, xz = 0.f, xn = 0.f;

    // ---- tid0: flag + credit waits ----
    if (tid == 0) {
      if (cell) {
        wait_ge(fA, (u32)(t + 1));
        if (t > 0) wait_ge(fB, (u32)t);
      } else if (func == 2) {
        wait_ge(fA, (u32)(t + 1));
        wait_ge(fB, (u32)(t + 1));
      }
      if (t >= DEPTH) {
        u32 need = (u32)(t - DEPTH + 1);
        if (cc0 < need) { do { cc0 = __hip_atomic_load(cO + 0, __ATOMIC_ACQUIRE, __HIP_MEMORY_SCOPE_AGENT); } while (cc0 < need); }
        if (nconsO > 1) {
          if (cc1 < need) { do { cc1 = __hip_atomic_load(cO + 1, __ATOMIC_ACQUIRE, __HIP_MEMORY_SCOPE_AGENT); } while (cc1 < need); }
          if (cc2 < need) { do { cc2 = __hip_atomic_load(cO + 2, __ATOMIC_ACQUIRE, __HIP_MEMORY_SCOPE_AGENT); } while (cc2 < need); }
        }
      }
    }
    __syncthreads();   // B1

    // ---- input fills / early gate loads ----
    if (func == 0) {
      if (tid < 128) hbu[(t & 1) * 128 + tid] = __builtin_bit_cast(u32, xreg);
    } else if (func == 2) {
      if (tid < 128) {
        const u32* src = (tid < 64) ? (hq_a + (size_t)slot * 64 + tid)
                                    : (hq_b + (size_t)slot * 64 + (tid - 64));
        hbu[(t & 1) * 128 + tid] = ld_u32_agent(src);
      }
    } else { // cells
      if (t > 0 && tid < 64) {
        u32 v = ld_u32_agent(hq_pn + (size_t)((t - 1) & (DEPTH - 1)) * 64 + tid);
        hbu[(t & 1) * 128 + (1 - half) * 64 + tid] = v;
      }
      if (c == 0) {   // gate inputs; consumed in epilogue (latency hidden by dot)
        const float* q = xg_in + (size_t)slot * 384;
        xr = ld_f32_agent(q + i);
        xz = ld_f32_agent(q + 128 + i);
        xn = ld_f32_agent(q + 256 + i);
      }
    }
    __syncthreads();   // B2

    if (func == 0 && tid < 128 && t + 1 < TT) {   // prefetch next x row
      float2 v = ((const float2*)(x + (size_t)(chain * TT + t + 1) * HH))[tid];
      xreg = f2h2(v.x, v.y);
    }

    // ---- GEMV: 3 rows x 64 k per thread, v_dot2_f32_f16 ----
    float a0 = 0.f, a1 = 0.f, a2 = 0.f;
    const float4* hv4 = (const float4*)&hb[t & 1][c * 32];
#pragma unroll
    for (int j4 = 0; j4 < 8; ++j4) {
      float4 q = hv4[j4];
      half2_t hh0 = __builtin_bit_cast(half2_t, q.x);
      half2_t hh1 = __builtin_bit_cast(half2_t, q.y);
      half2_t hh2 = __builtin_bit_cast(half2_t, q.z);
      half2_t hh3 = __builtin_bit_cast(half2_t, q.w);
      const int b0 = j4 * 4;
      a0 = __builtin_amdgcn_fdot2(__builtin_bit_cast(half2_t, w0[b0+0]), hh0, a0, false);
      a1 = __builtin_amdgcn_fdot2(__builtin_bit_cast(half2_t, w1[b0+0]), hh0, a1, false);
      a2 = __builtin_amdgcn_fdot2(__builtin_bit_cast(half2_t, w2[b0+0]), hh0, a2, false);
      a0 = __builtin_amdgcn_fdot2(__builtin_bit_cast(half2_t, w0[b0+1]), hh1, a0, false);
      a1 = __builtin_amdgcn_fdot2(__builtin_bit_cast(half2_t, w1[b0+1]), hh1, a1, false);
      a2 = __builtin_amdgcn_fdot2(__builtin_bit_cast(half2_t, w2[b0+1]), hh1, a2, false);
      a0 = __builtin_amdgcn_fdot2(__builtin_bit_cast(half2_t, w0[b0+2]), hh2, a0, false);
      a1 = __builtin_amdgcn_fdot2(__builtin_bit_cast(half2_t, w1[b0+2]), hh2, a1, false);
      a2 = __builtin_amdgcn_fdot2(__builtin_bit_cast(half2_t, w2[b0+2]), hh2, a2, false);
      a0 = __builtin_amdgcn_fdot2(__builtin_bit_cast(half2_t, w0[b0+3]), hh3, a0, false);
      a1 = __builtin_amdgcn_fdot2(__builtin_bit_cast(half2_t, w1[b0+3]), hh3, a1, false);
      a2 = __builtin_amdgcn_fdot2(__builtin_bit_cast(half2_t, w2[b0+3]), hh3, a2, false);
    }
    a0 += __shfl_xor(a0, 1, 64); a0 += __shfl_xor(a0, 2, 64);
    a1 += __shfl_xor(a1, 1, 64); a1 += __shfl_xor(a1, 2, 64);
    a2 += __shfl_xor(a2, 1, 64); a2 += __shfl_xor(a2, 2, 64);

    // ---- epilogue (c==0 lanes: one hidden unit each, i in [0,128)) ----
    if (c == 0) {
      if (!cell) {
        float* q = xg_out + (size_t)slot * 384;
        st_f32_agent(q + i,       a0 + bs0);
        st_f32_agent(q + 128 + i, a1 + bs1);
        st_f32_agent(q + 256 + i, a2 + bs2);
      } else {
        float r    = sigm(xr + a0 + bs0);
        float z    = sigm(xz + a1 + bs1);
        float n    = tanh_fast(xn + r * (a2 + bs2));
        float hnew = n + z * (hprev - n);
        hprev = hnew;
        half_t hv = (half_t)hnew;
        ((half_t*)&hb[(t + 1) & 1][0])[half * 128 + i] = hv;            // own half, next step
        st_u16_agent((u16*)(hq_out + (size_t)slot * 64) + i,            // publish to L2
                     __builtin_bit_cast(u16, hv));
        if (func == 3)
          out[(size_t)(chain * TT + t) * HH + half * 128 + i] = hnew;   // fp32 output
      }
    }
    __syncthreads();   // B3: drains all waves' stores (vmcnt(0) before s_barrier)

    if (tid == 0) {
      __hip_atomic_store(fO, (u32)(t + 1), __ATOMIC_RELEASE, __HIP_MEMORY_SCOPE_AGENT);
      if (cA) __hip_atomic_store(cA, (u32)(t + 1), __ATOMIC_RELAXED, __HIP_MEMORY_SCOPE_AGENT);
      if (cB) __hip_atomic_store(cB, (u32)(t + 1), __ATOMIC_RELAXED, __HIP_MEMORY_SCOPE_AGENT);
    }
  }
}

extern "C" void kernel_launch(void* const* d_in, const int* in_sizes, int n_in,
                              void* d_out, int out_size, void* d_ws, size_t ws_size,
                              hipStream_t stream) {
  hipMemsetAsync(d_ws, 0, FLAGS_BYTES, stream);   // zero flags/credits; capture-safe
  hipLaunchKernelGGL(gru_pipe, dim3(256), dim3(512), 0, stream,
                     (const float*)d_in[0], (const float*)d_in[1], (const float*)d_in[2],
                     (const float*)d_in[3], (const float*)d_in[4],
                     (float*)d_out, (uint8_t*)d_ws);
}

// Round 9
// 8839.665 us; speedup vs baseline: 1.8582x; 1.8582x over previous
//
#include <hip/hip_runtime.h>

typedef _Float16 half_t;
typedef _Float16 half2_t __attribute__((ext_vector_type(2)));
typedef unsigned int       u32;
typedef unsigned short     u16;

#define BB    32      // batch (chains)
#define TT    2048    // seq len
#define HH    256     // hidden = input dim
#define G3    768
#define DEPTH 8       // ring depth (power of 2)

// ws layout (bytes), total 1,736,704:
//   0       : flags[3 links][BB] monotonic u32, 128B pad   (12288, pad to 16384)
//   16384   : cons [3 links][BB] u32, 128B pad             (12288, pad to 32768)
//   32768   : xg0q [BB][DEPTH][G3] f32   (786432)          link 0 payload
//   819200  : xg1q [BB][DEPTH][G3] f32   (786432)          link 2 payload
//   1605632 : h0q  [BB][DEPTH][HH] f16   (131072)          link 1 payload
#define OFF_CONS 16384
#define OFF_XG0  32768
#define OFF_XG1  819200
#define OFF_H0   1605632
#define FLAGS_BYTES 32768

__device__ __forceinline__ half2_t f2h2(float a, float b) {
  half2_t r; r.x = (half_t)a; r.y = (half_t)b; return r;
}
__device__ __forceinline__ float sigm(float v) {
  return __builtin_amdgcn_rcpf(1.f + __builtin_amdgcn_exp2f(v * -1.4426950408889634f));
}
__device__ __forceinline__ float tanh_fast(float v) {
  return 1.f - 2.f * __builtin_amdgcn_rcpf(1.f + __builtin_amdgcn_exp2f(v * 2.8853900817779268f));
}
__device__ __forceinline__ void wait_ge(u32* p, u32 v) {
  while (__hip_atomic_load(p, __ATOMIC_ACQUIRE, __HIP_MEMORY_SCOPE_AGENT) < v) {}
}
__device__ __forceinline__ float ld_f32_agent(const float* p) {
  return __hip_atomic_load(p, __ATOMIC_RELAXED, __HIP_MEMORY_SCOPE_AGENT);
}
__device__ __forceinline__ u32 ld_u32_agent(const u32* p) {
  return __hip_atomic_load(p, __ATOMIC_RELAXED, __HIP_MEMORY_SCOPE_AGENT);
}
__device__ __forceinline__ void st_f32_agent(float* p, float v) {
  __hip_atomic_store(p, v, __ATOMIC_RELAXED, __HIP_MEMORY_SCOPE_AGENT);
}
__device__ __forceinline__ void st_u16_agent(u16* p, u16 v) {
  __hip_atomic_store(p, v, __ATOMIC_RELAXED, __HIP_MEMORY_SCOPE_AGENT);
}

// 128 blocks = 4 stages x 32 chains; blockIdx = stage*32 + chain (stage stride 32 ≡ 0 mod 8
// -> all stages of a chain on one XCD under round-robin dispatch).
//   stage 0: xg0 = Wih0@x_t + bih0       stage 1: cell0 (Whh0) — FULL cell in one block
//   stage 2: xg1 = Wih1@h0_t + bih1      stage 3: cell1 (Whh1) -> out (fp32)
// Design laws from R4-R8: (1) backend caps VGPRs at 128 — so 1024 threads, thread
// (i=tid>>2, c=tid&3) owns rows {i,256+i,512+i} x 64 k = 96 weight u32 + ~22 working
// regs, fitting 128 honestly (whole 512KB VGPR file = the 393KB weight tile, 1 block/CU);
// (2) asm-launder weights or they get rematerialized into the t-loop (R6);
// (3) recurrence never crosses blocks (R8's 2x regression) — only feed-forward links do,
// with DEPTH ring slack so L2 handoff latency pipelines away.
__global__ __launch_bounds__(1024) __attribute__((amdgpu_waves_per_eu(4, 4)))
void gru_pipe(const float* __restrict__ x,     // fp32 [B][T][H]
              const float* __restrict__ Wih,   // fp32 [2][768][256]
              const float* __restrict__ Whh,   // fp32 [2][768][256]
              const float* __restrict__ bih,   // fp32 [2][768]
              const float* __restrict__ bhh,   // fp32 [2][768]
              float* __restrict__ out,         // fp32 [B][T][H]
              uint8_t* __restrict__ ws)
{
  const int stage = blockIdx.x >> 5;
  const int chain = blockIdx.x & 31;
  const int tid   = threadIdx.x;
  const int i     = tid >> 2;     // 0..255 hidden unit
  const int c     = tid & 3;      // k-quarter
  const int layer = stage >> 1;
  const bool cell = stage & 1;

  u32*   flags = (u32*)ws;
  u32*   cons  = (u32*)(ws + OFF_CONS);
  float* xg0q  = (float*)(ws + OFF_XG0);
  float* xg1q  = (float*)(ws + OFF_XG1);
  u16*   h0q   = (u16*)(ws + OFF_H0);

  // links: 0 = xg0 (s0->s1), 1 = h0 (s1->s2), 2 = xg1 (s2->s3); stage s: in = s-1, out = s
  u32* flag_in  = (stage > 0) ? flags + (size_t)((stage - 1) * BB + chain) * 32 : nullptr;
  u32* flag_out = (stage < 3) ? flags + (size_t)(stage * BB + chain) * 32 : nullptr;
  u32* cons_in  = (stage > 0) ? cons + (size_t)((stage - 1) * BB + chain) * 32 : nullptr;
  u32* cons_out = (stage < 3) ? cons + (size_t)(stage * BB + chain) * 32 : nullptr;

  float* xg_in  = (stage == 1) ? xg0q + (size_t)chain * DEPTH * G3
                : (stage == 3) ? xg1q + (size_t)chain * DEPTH * G3 : nullptr;
  float* xg_out = (stage == 0) ? xg0q + (size_t)chain * DEPTH * G3
                : (stage == 2) ? xg1q + (size_t)chain * DEPTH * G3 : nullptr;
  u16*   hq     = h0q + (size_t)chain * DEPTH * HH;

  // ---- weights -> 96 VGPRs (fp32 -> f16 RNE), laundered against remat ----
  const float* Wm = (cell ? Whh : Wih) + (size_t)layer * G3 * HH;
  const float* bv = (cell ? bhh : bih) + (size_t)layer * G3;
  u32 w0[32], w1[32], w2[32];
  float bs0, bs1, bs2;
  {
    const float4* p0 = (const float4*)(Wm + (size_t)(i)       * HH + c * 64);
    const float4* p1 = (const float4*)(Wm + (size_t)(i + 256) * HH + c * 64);
    const float4* p2 = (const float4*)(Wm + (size_t)(i + 512) * HH + c * 64);
#pragma unroll
    for (int j = 0; j < 16; ++j) {
      float4 a = p0[j], b = p1[j], d = p2[j];
      w0[2*j] = __builtin_bit_cast(u32, f2h2(a.x, a.y)); w0[2*j+1] = __builtin_bit_cast(u32, f2h2(a.z, a.w));
      w1[2*j] = __builtin_bit_cast(u32, f2h2(b.x, b.y)); w1[2*j+1] = __builtin_bit_cast(u32, f2h2(b.z, b.w));
      w2[2*j] = __builtin_bit_cast(u32, f2h2(d.x, d.y)); w2[2*j+1] = __builtin_bit_cast(u32, f2h2(d.z, d.w));
    }
    bs0 = bv[i]; bs1 = bv[i + 256]; bs2 = bv[i + 512];
  }
#pragma unroll
  for (int j = 0; j < 32; ++j) {
    asm volatile("" : "+v"(w0[j]));
    asm volatile("" : "+v"(w1[j]));
    asm volatile("" : "+v"(w2[j]));
  }

  __shared__ __align__(16) u32 hbu[2][128];   // ping-pong 256-f16 input vector
  if (tid < 128) { hbu[0][tid] = 0u; hbu[1][tid] = 0u; }

  float   hprev = 0.f;
  half2_t xreg; xreg.x = (half_t)0.f; xreg.y = (half_t)0.f;
  if (stage == 0 && tid < 128) {
    float2 v = ((const float2*)(x + (size_t)(chain * TT) * HH))[tid];
    xreg = f2h2(v.x, v.y);
  }
  u32 credit = 0;   // tid0's cached view of cons_out

  __syncthreads();

  for (int t = 0; t < TT; ++t) {
    const int slot = t & (DEPTH - 1);
    float xr = 0.f, xz = 0.f, xn = 0.f;

    // ---- tid0: flag + credit waits (single poller) ----
    if (tid == 0) {
      if (stage > 0) wait_ge(flag_in, (u32)(t + 1));
      if (stage < 3 && t >= DEPTH) {
        u32 need = (u32)(t - DEPTH + 1);
        while (credit < need)
          credit = __hip_atomic_load(cons_out, __ATOMIC_ACQUIRE, __HIP_MEMORY_SCOPE_AGENT);
      }
    }
    __syncthreads();   // B1: released once inputs ready + ring slot free

    // ---- input fill / early gate loads ----
    if (stage == 0) {
      if (tid < 128) hbu[t & 1][tid] = __builtin_bit_cast(u32, xreg);
    } else if (stage == 2) {
      if (tid < 128)
        hbu[t & 1][tid] = ld_u32_agent((const u32*)(hq + (size_t)slot * HH) + tid);
    } else {   // cells: hb is self-maintained; fetch gate inputs (consumed after dot)
      if (c == 0) {
        const float* q = xg_in + (size_t)slot * G3;
        xr = ld_f32_agent(q + i);
        xz = ld_f32_agent(q + 256 + i);
        xn = ld_f32_agent(q + 512 + i);
      }
    }
    __syncthreads();   // B2: hb visible

    if (stage == 0 && tid < 128 && t + 1 < TT) {   // prefetch next x row
      float2 v = ((const float2*)(x + (size_t)(chain * TT + t + 1) * HH))[tid];
      xreg = f2h2(v.x, v.y);
    }

    // ---- GEMV: 3 rows x 64 k per thread, v_dot2_f32_f16 ----
    float a0 = 0.f, a1 = 0.f, a2 = 0.f;
    const float4* hv4 = (const float4*)&hbu[t & 1][c * 32];
#pragma unroll
    for (int j4 = 0; j4 < 8; ++j4) {
      float4 q = hv4[j4];
      half2_t hh0 = __builtin_bit_cast(half2_t, q.x);
      half2_t hh1 = __builtin_bit_cast(half2_t, q.y);
      half2_t hh2 = __builtin_bit_cast(half2_t, q.z);
      half2_t hh3 = __builtin_bit_cast(half2_t, q.w);
      const int b0 = j4 * 4;
      a0 = __builtin_amdgcn_fdot2(__builtin_bit_cast(half2_t, w0[b0+0]), hh0, a0, false);
      a1 = __builtin_amdgcn_fdot2(__builtin_bit_cast(half2_t, w1[b0+0]), hh0, a1, false);
      a2 = __builtin_amdgcn_fdot2(__builtin_bit_cast(half2_t, w2[b0+0]), hh0, a2, false);
      a0 = __builtin_amdgcn_fdot2(__builtin_bit_cast(half2_t, w0[b0+1]), hh1, a0, false);
      a1 = __builtin_amdgcn_fdot2(__builtin_bit_cast(half2_t, w1[b0+1]), hh1, a1, false);
      a2 = __builtin_amdgcn_fdot2(__builtin_bit_cast(half2_t, w2[b0+1]), hh1, a2, false);
      a0 = __builtin_amdgcn_fdot2(__builtin_bit_cast(half2_t, w0[b0+2]), hh2, a0, false);
      a1 = __builtin_amdgcn_fdot2(__builtin_bit_cast(half2_t, w1[b0+2]), hh2, a1, false);
      a2 = __builtin_amdgcn_fdot2(__builtin_bit_cast(half2_t, w2[b0+2]), hh2, a2, false);
      a0 = __builtin_amdgcn_fdot2(__builtin_bit_cast(half2_t, w0[b0+3]), hh3, a0, false);
      a1 = __builtin_amdgcn_fdot2(__builtin_bit_cast(half2_t, w1[b0+3]), hh3, a1, false);
      a2 = __builtin_amdgcn_fdot2(__builtin_bit_cast(half2_t, w2[b0+3]), hh3, a2, false);
    }
    a0 += __shfl_xor(a0, 1, 64); a0 += __shfl_xor(a0, 2, 64);
    a1 += __shfl_xor(a1, 1, 64); a1 += __shfl_xor(a1, 2, 64);
    a2 += __shfl_xor(a2, 1, 64); a2 += __shfl_xor(a2, 2, 64);

    // ---- epilogue (c==0 lanes: one hidden unit each) ----
    if (c == 0) {
      if (!cell) {
        float* q = xg_out + (size_t)slot * G3;
        st_f32_agent(q + i,       a0 + bs0);
        st_f32_agent(q + 256 + i, a1 + bs1);
        st_f32_agent(q + 512 + i, a2 + bs2);
      } else {
        float r    = sigm(xr + a0 + bs0);
        float z    = sigm(xz + a1 + bs1);
        float n    = tanh_fast(xn + r * (a2 + bs2));
        float hnew = n + z * (hprev - n);
        hprev = hnew;
        half_t hv = (half_t)hnew;
        ((half_t*)&hbu[(t + 1) & 1][0])[i] = hv;          // own state, next step (in-block)
        if (stage == 1)
          st_u16_agent(hq + (size_t)slot * HH + i, __builtin_bit_cast(u16, hv));
        else
          out[(size_t)(chain * TT + t) * HH + i] = hnew;  // fp32 output
      }
    }
    __syncthreads();   // B3: drains all waves' stores (vmcnt(0) before s_barrier)

    if (tid == 0) {
      if (stage < 3)
        __hip_atomic_store(flag_out, (u32)(t + 1), __ATOMIC_RELEASE, __HIP_MEMORY_SCOPE_AGENT);
      if (stage > 0)
        __hip_atomic_store(cons_in, (u32)(t + 1), __ATOMIC_RELAXED, __HIP_MEMORY_SCOPE_AGENT);
    }
  }
}

extern "C" void kernel_launch(void* const* d_in, const int* in_sizes, int n_in,
                              void* d_out, int out_size, void* d_ws, size_t ws_size,
                              hipStream_t stream) {
  hipMemsetAsync(d_ws, 0, FLAGS_BYTES, stream);   // zero flags/credits; capture-safe
  hipLaunchKernelGGL(gru_pipe, dim3(128), dim3(1024), 0, stream,
                     (const float*)d_in[0], (const float*)d_in[1], (const float*)d_in[2],
                     (const float*)d_in[3], (const float*)d_in[4],
                     (float*)d_out, (uint8_t*)d_ws);
}